// Round 4
// baseline (212.009 us; speedup 1.0000x reference)
//
#include <hip/hip_runtime.h>
#include <cmath>

#define NPTS 262144
#define NLVL 16
#define NDENSE 5
#define NHASH 11
#define HASH_MASK 0x7FFFFu

#define PPT 4                            // points per thread in enc_hash
#define CHUNK (256 * PPT)                // 1024 points per block
#define CHUNKS_PER_LVL (NPTS / CHUNK)    // 256
#define TOTAL_UNITS (NHASH * CHUNKS_PER_LVL)  // 2816
#define UNITS_PER_XCD (TOTAL_UNITS / 8)       // 352

struct MetaD { float scale[NDENSE]; unsigned off[NDENSE]; unsigned res[NDENSE]; };
struct MetaH { float scale[NHASH]; unsigned off[NHASH]; };

// ---------------- hash levels 5..15 (hsize = 2^19, pow2 mask) ----------------
// XCD-affine, exactly balanced: block b -> xcd = b&7 (HW round-robin), unit
// g = xcd*352 + (b>>3); level = g/256, chunk = g%256. Each XCD does 352 units
// and walks <=3 level tables sequentially (4 MB each through its L2).
__global__ __launch_bounds__(256) void enc_hash(
    const float* __restrict__ means, const float* __restrict__ emb,
    float2* __restrict__ dst, int lvl_major, MetaH meta)
{
    const unsigned b   = blockIdx.x;
    const unsigned g   = (b & 7u) * UNITS_PER_XCD + (b >> 3);
    const unsigned il  = g >> 8;          // / CHUNKS_PER_LVL
    const unsigned chk = g & 255u;

    const float sc     = meta.scale[il];
    const unsigned off = meta.off[il];
    const unsigned lvl = il + NDENSE;

    const unsigned p0 = chk * CHUNK + threadIdx.x;
    const float2* __restrict__ emb2 = (const float2*)emb;

#pragma unroll
    for (int pp = 0; pp < PPT; ++pp) {
        const unsigned p = p0 + (unsigned)pp * 256u;

        const float x = (means[3 * p + 0] + 1.0f) * 0.5f;
        const float y = (means[3 * p + 1] + 1.0f) * 0.5f;
        const float z = (means[3 * p + 2] + 1.0f) * 0.5f;

        const float px = x * sc, py = y * sc, pz = z * sc;
        const float gx = floorf(px), gy = floorf(py), gz = floorf(pz);
        const float fx = px - gx, fy = py - gy, fz = pz - gz;
        const unsigned ix = (unsigned)gx, iy = (unsigned)gy, iz = (unsigned)gz;

        const unsigned hy0 = iy * 2654435761u, hy1 = hy0 + 2654435761u;
        const unsigned hz0 = iz * 805459861u,  hz1 = hz0 + 805459861u;
        const unsigned x0 = ix, x1 = ix + 1u;

        // all 8 indices up front, then 8 independent gathers (no divergence)
        unsigned idx[8];
        idx[0] = (x0 ^ hy0 ^ hz0) & HASH_MASK;
        idx[1] = (x1 ^ hy0 ^ hz0) & HASH_MASK;
        idx[2] = (x0 ^ hy1 ^ hz0) & HASH_MASK;
        idx[3] = (x1 ^ hy1 ^ hz0) & HASH_MASK;
        idx[4] = (x0 ^ hy0 ^ hz1) & HASH_MASK;
        idx[5] = (x1 ^ hy0 ^ hz1) & HASH_MASK;
        idx[6] = (x0 ^ hy1 ^ hz1) & HASH_MASK;
        idx[7] = (x1 ^ hy1 ^ hz1) & HASH_MASK;

        float2 f[8];
#pragma unroll
        for (int c = 0; c < 8; ++c)
            f[c] = emb2[off + idx[c]];

        const float wx0 = 1.0f - fx, wy0 = 1.0f - fy, wz0 = 1.0f - fz;
        const float w00 = wz0 * wy0, w01 = wz0 * fy, w10 = fz * wy0, w11 = fz * fy;
        const float a0 = w00 * (wx0 * f[0].x + fx * f[1].x) + w01 * (wx0 * f[2].x + fx * f[3].x)
                       + w10 * (wx0 * f[4].x + fx * f[5].x) + w11 * (wx0 * f[6].x + fx * f[7].x);
        const float a1 = w00 * (wx0 * f[0].y + fx * f[1].y) + w01 * (wx0 * f[2].y + fx * f[3].y)
                       + w10 * (wx0 * f[4].y + fx * f[5].y) + w11 * (wx0 * f[6].y + fx * f[7].y);

        const size_t di = lvl_major ? ((size_t)il * NPTS + p) : ((size_t)p * NLVL + lvl);
        dst[di] = make_float2(a0, a1);
    }
}

// ------- finalize: dense levels 0..4 inline + gather hash results from ws,
//         write full 128 B lines point-major -------
__global__ __launch_bounds__(256) void finalize(
    const float* __restrict__ means, const float* __restrict__ emb,
    const float2* __restrict__ ws, float* __restrict__ out, MetaD meta)
{
    const int p = blockIdx.x * 256 + threadIdx.x;

    float2 o2[NLVL];

    // issue the 11 coalesced ws reads first (long latency, independent)
#pragma unroll
    for (int il = 0; il < NHASH; ++il)
        o2[NDENSE + il] = ws[(size_t)il * NPTS + p];

    const float x = (means[3 * p + 0] + 1.0f) * 0.5f;
    const float y = (means[3 * p + 1] + 1.0f) * 0.5f;
    const float z = (means[3 * p + 2] + 1.0f) * 0.5f;

    const float2* __restrict__ emb2 = (const float2*)emb;

#pragma unroll
    for (int l = 0; l < NDENSE; ++l) {
        const float s      = meta.scale[l];
        const unsigned off = meta.off[l];
        const unsigned r   = meta.res[l];

        const float px = x * s, py = y * s, pz = z * s;
        const float gx = floorf(px), gy = floorf(py), gz = floorf(pz);
        const float fx = px - gx, fy = py - gy, fz = pz - gz;
        const unsigned ix = (unsigned)gx, iy = (unsigned)gy, iz = (unsigned)gz;

        const unsigned base = ix + iy * r + iz * r * r + off;
        const unsigned dy = r, dz = r * r;

        float2 f[8];
        f[0] = emb2[base];           f[1] = emb2[base + 1];
        f[2] = emb2[base + dy];      f[3] = emb2[base + dy + 1];
        f[4] = emb2[base + dz];      f[5] = emb2[base + dz + 1];
        f[6] = emb2[base + dz + dy]; f[7] = emb2[base + dz + dy + 1];

        const float wx0 = 1.0f - fx, wy0 = 1.0f - fy, wz0 = 1.0f - fz;
        const float w00 = wz0 * wy0, w01 = wz0 * fy, w10 = fz * wy0, w11 = fz * fy;
        o2[l].x = w00 * (wx0 * f[0].x + fx * f[1].x) + w01 * (wx0 * f[2].x + fx * f[3].x)
                + w10 * (wx0 * f[4].x + fx * f[5].x) + w11 * (wx0 * f[6].x + fx * f[7].x);
        o2[l].y = w00 * (wx0 * f[0].y + fx * f[1].y) + w01 * (wx0 * f[2].y + fx * f[3].y)
                + w10 * (wx0 * f[4].y + fx * f[5].y) + w11 * (wx0 * f[6].y + fx * f[7].y);
    }

    float4* out4 = (float4*)(out + (size_t)p * (2 * NLVL));
    const float4* src = (const float4*)o2;
#pragma unroll
    for (int k = 0; k < 8; ++k)
        out4[k] = src[k];
}

// fallback dense kernel (only used if ws is too small for level-major staging)
__global__ __launch_bounds__(256) void enc_dense_direct(
    const float* __restrict__ means, const float* __restrict__ emb,
    float2* __restrict__ dst, MetaD meta)
{
    const int p = blockIdx.x * 256 + threadIdx.x;
    const int l = blockIdx.y;

    const float x = (means[3 * p + 0] + 1.0f) * 0.5f;
    const float y = (means[3 * p + 1] + 1.0f) * 0.5f;
    const float z = (means[3 * p + 2] + 1.0f) * 0.5f;

    const float s      = meta.scale[l];
    const unsigned off = meta.off[l];
    const unsigned r   = meta.res[l];

    const float px = x * s, py = y * s, pz = z * s;
    const float gx = floorf(px), gy = floorf(py), gz = floorf(pz);
    const float fx = px - gx, fy = py - gy, fz = pz - gz;
    const unsigned ix = (unsigned)gx, iy = (unsigned)gy, iz = (unsigned)gz;

    const unsigned base = ix + iy * r + iz * r * r + off;
    const unsigned dy = r, dz = r * r;

    const float2* __restrict__ emb2 = (const float2*)emb;
    float2 f[8];
    f[0] = emb2[base];           f[1] = emb2[base + 1];
    f[2] = emb2[base + dy];      f[3] = emb2[base + dy + 1];
    f[4] = emb2[base + dz];      f[5] = emb2[base + dz + 1];
    f[6] = emb2[base + dz + dy]; f[7] = emb2[base + dz + dy + 1];

    const float wx0 = 1.0f - fx, wy0 = 1.0f - fy, wz0 = 1.0f - fz;
    const float w00 = wz0 * wy0, w01 = wz0 * fy, w10 = fz * wy0, w11 = fz * fy;
    const float a0 = w00 * (wx0 * f[0].x + fx * f[1].x) + w01 * (wx0 * f[2].x + fx * f[3].x)
                   + w10 * (wx0 * f[4].x + fx * f[5].x) + w11 * (wx0 * f[6].x + fx * f[7].x);
    const float a1 = w00 * (wx0 * f[0].y + fx * f[1].y) + w01 * (wx0 * f[2].y + fx * f[3].y)
                   + w10 * (wx0 * f[4].y + fx * f[5].y) + w11 * (wx0 * f[6].y + fx * f[7].y);

    dst[(size_t)p * NLVL + l] = make_float2(a0, a1);
}

extern "C" void kernel_launch(void* const* d_in, const int* in_sizes, int n_in,
                              void* d_out, int out_size, void* d_ws, size_t ws_size,
                              hipStream_t stream)
{
    const float* means = (const float*)d_in[0];
    const float* emb   = (const float*)d_in[1];
    float* out         = (float*)d_out;

    MetaD md;
    MetaH mh;
    const double lg = log2(1.38191288);
    unsigned off = 0;
    for (int l = 0; l < NLVL; ++l) {
        const double scale_d = pow(2.0, (double)l * lg) * 16.0 - 1.0;
        const unsigned res_enc = (unsigned)ceil(scale_d) + 1u;

        const double gres_d = ceil(16.0 * pow(1.38191288, (double)l));
        unsigned long long r3 = (unsigned long long)gres_d;
        r3 = r3 * r3 * r3;
        unsigned long long pl = r3 < (1ull << 19) ? r3 : (1ull << 19);
        pl = (pl + 7ull) / 8ull * 8ull;

        if (l < NDENSE) {
            md.scale[l] = (float)scale_d;
            md.off[l]   = off;
            md.res[l]   = res_enc;
        } else {
            mh.scale[l - NDENSE] = (float)scale_d;
            mh.off[l - NDENSE]   = off;
        }
        off += (unsigned)pl;
    }

    const size_t ws_needed = (size_t)NHASH * NPTS * sizeof(float2);  // 23 MB
    if (ws_size >= ws_needed) {
        float2* ws = (float2*)d_ws;
        enc_hash<<<TOTAL_UNITS, 256, 0, stream>>>(means, emb, ws, 1, mh);
        finalize<<<NPTS / 256, 256, 0, stream>>>(means, emb, ws, out, md);
    } else {
        enc_hash<<<TOTAL_UNITS, 256, 0, stream>>>(means, emb, (float2*)out, 0, mh);
        enc_dense_direct<<<dim3(NPTS / 256, NDENSE, 1), 256, 0, stream>>>(means, emb, (float2*)out, md);
    }
}